// Round 2
// baseline (2662.323 us; speedup 1.0000x reference)
//
#include <hip/hip_runtime.h>
#include <cmath>

// ConvLSTM round 9: persistent kernel for all 16 steps with a MANUAL grid
// barrier (device-scope atomics + __threadfence), since
// hipLaunchCooperativeKernel is not graph-capturable (round-8 failure: the
// coop launch errored silently and the kernel never ran).
// Cell state lives in registers for the whole sequence; h ping-pongs through
// global bf16 buffers. Grid 512 blocks = 2/CU co-resident by construction
// (__launch_bounds__(256,2) caps VGPR at 256; LDS 51.8KB <= 80KB/block).

#define CHW 262144             // 64*64*64
#define ZSZ 12960              // ushorts per z buffer (324*40)
#define NBLK 512u

typedef short bf16x8 __attribute__((ext_vector_type(8)));
typedef float f32x4  __attribute__((ext_vector_type(4)));

static __device__ __forceinline__ ushort f2bf(float f) {
    union { float f; unsigned u; } v; v.f = f;
    unsigned u = v.u;
    return (ushort)((u + 0x7FFFu + ((u >> 16) & 1u)) >> 16);
}
static __device__ __forceinline__ float bf2f(ushort u) {
    union { unsigned u; float f; } v; v.u = (unsigned)u << 16; return v.f;
}
static __device__ __forceinline__ float sigf(float x) {
    return 1.f / (1.f + __expf(-x));
}

// Wt layout: [cq = cix*4+q][tap][g][lane][8j] (ushort).
// element = bf16(Wk[oc = g*64+q*16+(lane&15)][ic = cix*32+(lane>>4)*8+j][ky][kx])
__global__ void transform_w(const float* __restrict__ Wk, ushort* __restrict__ Wt) {
    const int idx  = blockIdx.x * 256 + threadIdx.x;   // 0..36863
    const int lane = idx & 63;
    const int g    = (idx >> 6) & 3;
    const int r2   = idx >> 8;
    const int tap  = r2 % 9;
    const int cq   = r2 / 9;
    const int q    = cq & 3;
    const int cix  = cq >> 2;
    const int oc   = g * 64 + q * 16 + (lane & 15);
    const int icb  = cix * 32 + (lane >> 4) * 8;
    const int ky   = tap / 3, kx = tap - ky * 3;
    ushort* dst = Wt + (size_t)idx * 8;
    #pragma unroll
    for (int j = 0; j < 8; ++j)
        dst[j] = f2bf(Wk[((size_t)(oc * 128 + icb + j) * 3 + ky) * 3 + kx]);
}

// x (8,16,64,64,64) fp32 NCHW -> xb (8,16,4096,64) bf16 NHWC (per bt volume)
__global__ __launch_bounds__(256) void xconv(const float* __restrict__ x,
                                             ushort* __restrict__ xb) {
    __shared__ ushort T[256 * 66];
    const int tid = threadIdx.x;
    const int pg  = blockIdx.x;        // 16 pixel-groups of 256
    const int bt  = blockIdx.y;        // 128
    const float* xt = x  + (size_t)bt * CHW;
    ushort*      xo = xb + (size_t)bt * CHW;
    const int p0 = pg * 256;
    #pragma unroll
    for (int ch = 0; ch < 64; ++ch)
        T[tid * 66 + ch] = f2bf(xt[(size_t)ch * 4096 + p0 + tid]);
    __syncthreads();
    #pragma unroll
    for (int k = 0; k < 64; ++k) {
        const int item = k * 256 + tid;
        const int px = item >> 6, ch = item & 63;
        xo[(size_t)(p0 + px) * 64 + ch] = T[px * 66 + ch];
    }
}

// stage one 32-channel haloed 18x18 chunk from NHWC bf16 src into LDS buffer
static __device__ __forceinline__ void stage_chunk(
    ushort* __restrict__ dst, const ushort* __restrict__ src,
    int tid, int ty0, int tx0) {
    #pragma unroll
    for (int k = 0; k < 11; ++k) {
        const int i = tid + k * 256;
        if (i < 2592) {
            const int p   = i >> 3;
            const int icq = i & 7;
            const int py  = p / 18;
            const int pxl = p - py * 18;
            const int gy  = ty0 + py - 1;
            const int gx  = tx0 + pxl - 1;
            ushort4 v = {0, 0, 0, 0};
            if (((unsigned)gy < 64u) & ((unsigned)gx < 64u))
                v = *(const ushort4*)&src[(size_t)(gy * 64 + gx) * 64 + icq * 4];
            *(ushort4*)&dst[p * 40 + icq * 4] = v;
        }
    }
}

__global__ __launch_bounds__(256, 2) void convlstm_all(
    const ushort* __restrict__ xb,    // (8,16,4096,64) bf16 NHWC
    const ushort* __restrict__ Wt,    // fragment-ordered bf16 weights
    ushort*       __restrict__ hb0,   // (8,4096,64) bf16 NHWC ping
    ushort*       __restrict__ hb1,   // (8,4096,64) bf16 NHWC pong
    float*        __restrict__ cell,  // (8,4096,64) fp32 NHWC, final only
    unsigned*     __restrict__ bar)   // 15 zeroed per-step barrier counters
{
    __shared__ __align__(16) ushort zs[2 * ZSZ];      // 51,840 B double buffer

    const int tid  = threadIdx.x;
    const int lane = tid & 63;
    const int w    = tid >> 6;
    const int col  = lane & 15;
    const int quad = lane >> 4;
    const int q8   = quad * 8;

    const int tile = blockIdx.x;
    const int ty0  = (tile >> 2) * 16;
    const int tx0  = (tile & 3) * 16;
    const int q    = blockIdx.y;
    const int hc0  = q * 16;
    const int b    = blockIdx.z;

    ushort* h0 = hb0 + (size_t)b * CHW;
    ushort* h1 = hb1 + (size_t)b * CHW;
    float*  cb = cell + (size_t)b * CHW;

    const int gy_ = ty0 + 4 * w;
    const int gx_ = tx0 + quad * 4;
    const ushort* wq = Wt + (size_t)q * 18432;

    // cell lives in registers across all 16 steps
    f32x4 cpv[4];
    #pragma unroll
    for (int r = 0; r < 4; ++r)
        cpv[r] = (f32x4){0.f, 0.f, 0.f, 0.f};

    for (int t = 0; t < 16; ++t) {
        const ushort* xt = xb + ((size_t)b * 16 + t) * CHW;
        const ushort* hi = (t & 1) ? h1 : h0;   // written at step t-1
        ushort*       ho = (t & 1) ? h0 : h1;

        f32x4 acc[4][4];
        #pragma unroll
        for (int r = 0; r < 4; ++r)
            #pragma unroll
            for (int g = 0; g < 4; ++g)
                acc[r][g] = (f32x4){0.f, 0.f, 0.f, 0.f};

        // chunk sources: 0,1 -> x channels 0-31/32-63; 2,3 -> h channels 0-31/32-63
        stage_chunk(zs, xt, tid, ty0, tx0);
        __syncthreads();

        #pragma unroll
        for (int cix = 0; cix < 4; ++cix) {
            ushort* cur = zs + (cix & 1) * ZSZ;
            ushort* nxt = zs + ((cix + 1) & 1) * ZSZ;

            // stage next chunk into the idle buffer (no barrier: nxt unread
            // this iter); compiler interleaves these with the MFMAs below.
            if (cix == 0) stage_chunk(nxt, xt + 32, tid, ty0, tx0);
            else if (cix == 1) stage_chunk(nxt, hi, tid, ty0, tx0);
            else if (cix == 2) stage_chunk(nxt, hi + 32, tid, ty0, tx0);

            const ushort* wb = wq + (size_t)cix * 4 * 18432;
            #pragma unroll
            for (int kx = 0; kx < 3; ++kx) {
                bf16x8 arow[6];
                #pragma unroll
                for (int j = 0; j < 6; ++j)
                    arow[j] = *(const bf16x8*)&cur[((4 * w + j) * 18 + col + kx) * 40 + q8];
                #pragma unroll
                for (int ky = 0; ky < 3; ++ky) {
                    const int tap = ky * 3 + kx;
                    bf16x8 bfr[4];
                    #pragma unroll
                    for (int g = 0; g < 4; ++g)
                        bfr[g] = *(const bf16x8*)(wb + (size_t)tap * 2048 + g * 512 + lane * 8);
                    #pragma unroll
                    for (int g = 0; g < 4; ++g)
                        #pragma unroll
                        for (int r = 0; r < 4; ++r)
                            acc[r][g] = __builtin_amdgcn_mfma_f32_16x16x32_bf16(
                                arow[r + ky], bfr[g], acc[r][g], 0, 0, 0);
                }
            }
            __syncthreads();   // nxt fully written & cur fully read before swap
        }

        // epilogue: gates + state update; cell stays in registers
        #pragma unroll
        for (int r = 0; r < 4; ++r) {
            const size_t rowbase = ((size_t)(gy_ + r) * 64 + gx_) * 64 + hc0 + col;
            #pragma unroll
            for (int reg = 0; reg < 4; ++reg) {
                const float ci  = acc[r][0][reg];
                const float cf  = acc[r][1][reg];
                const float co  = acc[r][2][reg];
                const float cgv = acc[r][3][reg];
                const float cn  = sigf(cf) * cpv[r][reg] + sigf(ci) * tanhf(cgv);
                const float hn  = sigf(co) * tanhf(cn);
                cpv[r][reg] = cn;
                ho[rowbase + (size_t)reg * 64] = f2bf(hn);
                if (t == 15) cb[rowbase + (size_t)reg * 64] = cn;
            }
        }

        if (t < 15) {
            // -------- manual grid barrier (device scope, per-step counter) ----
            __syncthreads();                   // all waves' h stores drained to L2
            if (tid == 0) {
                __threadfence();               // release: L2 writeback past XCD
                atomicAdd(&bar[t], 1u);        // device-scope arrive
                while (__hip_atomic_load(&bar[t], __ATOMIC_RELAXED,
                                         __HIP_MEMORY_SCOPE_AGENT) < NBLK)
                    __builtin_amdgcn_s_sleep(2);
            }
            __syncthreads();                   // block released by tid 0
            __threadfence();                   // acquire: invalidate stale L1/L2
        }
    }
}

// NHWC -> NCHW final outputs: d_out = [h fp32 | c fp32], each (8,64,4096)
__global__ __launch_bounds__(256) void conv_out(
    const ushort* __restrict__ hN, const float* __restrict__ cN,
    float* __restrict__ out)
{
    __shared__ float T[64][65];
    const int tid  = threadIdx.x;
    const int pg   = blockIdx.x;        // 64 pixel-groups of 64
    const int b    = blockIdx.y;
    const int tsel = blockIdx.z;        // 0 = h, 1 = c
    const int pix0 = pg * 64;

    #pragma unroll
    for (int k = 0; k < 16; ++k) {
        const int idx = k * 256 + tid;
        const int pl = idx >> 6, ch = idx & 63;
        const size_t src = (size_t)b * CHW + (size_t)(pix0 + pl) * 64 + ch;
        T[pl][ch] = tsel ? cN[src] : bf2f(hN[src]);
    }
    __syncthreads();
    float* base = out + (tsel ? 2097152 : 0);
    #pragma unroll
    for (int k = 0; k < 16; ++k) {
        const int idx = k * 256 + tid;
        const int ch = idx >> 6, pl = idx & 63;
        base[(size_t)b * CHW + (size_t)ch * 4096 + pix0 + pl] = T[pl][ch];
    }
}

extern "C" void kernel_launch(void* const* d_in, const int* in_sizes, int n_in,
                              void* d_out, int out_size, void* d_ws, size_t ws_size,
                              hipStream_t stream) {
    const float* x  = (const float*)d_in[0];
    const float* Wk = (const float*)d_in[1];
    float* out = (float*)d_out;

    char* ws = (char*)d_ws;
    ushort*   Wt  = (ushort*)ws;                       // 589,824 B @ 0
    unsigned* bar = (unsigned*)(ws + 917504);          // 64 B @ 896 KB
    float*    cb  = (float*)(ws + (1u << 20));         // 8,388,608 B @ 1 MB
    ushort*   hb0 = (ushort*)(ws + (16u << 20));       // 4,194,304 B @ 16 MB
    ushort*   hb1 = (ushort*)(ws + (20u << 20));       // 4,194,304 B @ 20 MB
    ushort*   xb  = (ushort*)(ws + (32u << 20));       // 67,108,864 B @ 32 MB

    (void)hipMemsetAsync(hb0, 0, 4194304, stream);     // h(-1) = 0
    (void)hipMemsetAsync(bar, 0, 64, stream);          // barrier counters
    transform_w<<<144, 256, 0, stream>>>(Wk, Wt);
    xconv<<<dim3(16, 128), 256, 0, stream>>>(x, xb);

    convlstm_all<<<dim3(16, 4, 8), 256, 0, stream>>>(xb, Wt, hb0, hb1, cb, bar);

    // t=15 wrote hb0
    conv_out<<<dim3(64, 8, 2), 256, 0, stream>>>(hb0, cb, out);
}

// Round 3
// 2119.761 us; speedup vs baseline: 1.2560x; 1.2560x over previous
//
#include <hip/hip_runtime.h>
#include <cmath>

// ConvLSTM round 10: persistent kernel, SELECTIVE coherence.
// Round-9 post-mortem: __threadfence() (acq_rel, agent) lowers to buffer_inv
// -> cache-wide L2 invalidate every step by every block -> 2.37 GB refetch
// (weights/x/h all re-pulled from HBM 16x). Fix:
//  - release side: __hip_atomic_fetch_add(RELEASE, AGENT) = buffer_wbl2
//    (write-back, no invalidate) + atomic. L2 stays valid.
//  - acquire side: NO fence. Only h is cross-block mutable; h staging loads
//    are agent-scope relaxed atomic 8B loads (sc1 -> served coherently from
//    Infinity Cache). Weights/x keep plain cached loads, warm all 16 steps.
//  - per-(t,batch) barrier counters (64 arrivals): batches are independent
//    chains, don't serialize them against each other.
// Cell state stays in registers for all 16 steps. Co-residency of the 512
// blocks (2/CU) was empirically proven by round 9.

#define CHW 262144             // 64*64*64
#define ZSZ 12960              // ushorts per z buffer (324*40)
#define BBLK 64u               // blocks per batch (16 tiles x 4 quarters)

typedef short bf16x8 __attribute__((ext_vector_type(8)));
typedef float f32x4  __attribute__((ext_vector_type(4)));

static __device__ __forceinline__ ushort f2bf(float f) {
    union { float f; unsigned u; } v; v.f = f;
    unsigned u = v.u;
    return (ushort)((u + 0x7FFFu + ((u >> 16) & 1u)) >> 16);
}
static __device__ __forceinline__ float bf2f(ushort u) {
    union { unsigned u; float f; } v; v.u = (unsigned)u << 16; return v.f;
}
static __device__ __forceinline__ float sigf(float x) {
    return 1.f / (1.f + __expf(-x));
}

// Wt layout: [cq = cix*4+q][tap][g][lane][8j] (ushort).
// element = bf16(Wk[oc = g*64+q*16+(lane&15)][ic = cix*32+(lane>>4)*8+j][ky][kx])
__global__ void transform_w(const float* __restrict__ Wk, ushort* __restrict__ Wt) {
    const int idx  = blockIdx.x * 256 + threadIdx.x;   // 0..36863
    const int lane = idx & 63;
    const int g    = (idx >> 6) & 3;
    const int r2   = idx >> 8;
    const int tap  = r2 % 9;
    const int cq   = r2 / 9;
    const int q    = cq & 3;
    const int cix  = cq >> 2;
    const int oc   = g * 64 + q * 16 + (lane & 15);
    const int icb  = cix * 32 + (lane >> 4) * 8;
    const int ky   = tap / 3, kx = tap - ky * 3;
    ushort* dst = Wt + (size_t)idx * 8;
    #pragma unroll
    for (int j = 0; j < 8; ++j)
        dst[j] = f2bf(Wk[((size_t)(oc * 128 + icb + j) * 3 + ky) * 3 + kx]);
}

// x (8,16,64,64,64) fp32 NCHW -> xb (8,16,4096,64) bf16 NHWC (per bt volume)
__global__ __launch_bounds__(256) void xconv(const float* __restrict__ x,
                                             ushort* __restrict__ xb) {
    __shared__ ushort T[256 * 66];
    const int tid = threadIdx.x;
    const int pg  = blockIdx.x;        // 16 pixel-groups of 256
    const int bt  = blockIdx.y;        // 128
    const float* xt = x  + (size_t)bt * CHW;
    ushort*      xo = xb + (size_t)bt * CHW;
    const int p0 = pg * 256;
    #pragma unroll
    for (int ch = 0; ch < 64; ++ch)
        T[tid * 66 + ch] = f2bf(xt[(size_t)ch * 4096 + p0 + tid]);
    __syncthreads();
    #pragma unroll
    for (int k = 0; k < 64; ++k) {
        const int item = k * 256 + tid;
        const int px = item >> 6, ch = item & 63;
        xo[(size_t)(p0 + px) * 64 + ch] = T[px * 66 + ch];
    }
}

// stage one 32-channel haloed 18x18 chunk from NHWC bf16 src into LDS buffer.
// COH=true: agent-scope coherent loads (for h, written by other blocks/XCDs
// this kernel). COH=false: plain cached loads (x, weights era data).
template <bool COH>
static __device__ __forceinline__ void stage_chunk(
    ushort* __restrict__ dst, const ushort* __restrict__ src,
    int tid, int ty0, int tx0) {
    #pragma unroll
    for (int k = 0; k < 11; ++k) {
        const int i = tid + k * 256;
        if (i < 2592) {
            const int p   = i >> 3;
            const int icq = i & 7;
            const int py  = p / 18;
            const int pxl = p - py * 18;
            const int gy  = ty0 + py - 1;
            const int gx  = tx0 + pxl - 1;
            ushort4 v = {0, 0, 0, 0};
            if (((unsigned)gy < 64u) & ((unsigned)gx < 64u)) {
                const size_t off = (size_t)(gy * 64 + gx) * 64 + icq * 4;
                if constexpr (COH) {
                    union { unsigned long long u; ushort4 v4; } cv;
                    cv.u = __hip_atomic_load(
                        (const unsigned long long*)&src[off],
                        __ATOMIC_RELAXED, __HIP_MEMORY_SCOPE_AGENT);
                    v = cv.v4;
                } else {
                    v = *(const ushort4*)&src[off];
                }
            }
            *(ushort4*)&dst[p * 40 + icq * 4] = v;
        }
    }
}

__global__ __launch_bounds__(256, 2) void convlstm_all(
    const ushort* __restrict__ xb,    // (8,16,4096,64) bf16 NHWC
    const ushort* __restrict__ Wt,    // fragment-ordered bf16 weights
    ushort*       __restrict__ hb0,   // (8,4096,64) bf16 NHWC ping
    ushort*       __restrict__ hb1,   // (8,4096,64) bf16 NHWC pong
    float*        __restrict__ cell,  // (8,4096,64) fp32 NHWC, final only
    unsigned*     __restrict__ bar)   // 15*8 zeroed per-(step,batch) counters
{
    __shared__ __align__(16) ushort zs[2 * ZSZ];      // 51,840 B double buffer

    const int tid  = threadIdx.x;
    const int lane = tid & 63;
    const int w    = tid >> 6;
    const int col  = lane & 15;
    const int quad = lane >> 4;
    const int q8   = quad * 8;

    const int tile = blockIdx.x;
    const int ty0  = (tile >> 2) * 16;
    const int tx0  = (tile & 3) * 16;
    const int q    = blockIdx.y;
    const int hc0  = q * 16;
    const int b    = blockIdx.z;

    ushort* h0 = hb0 + (size_t)b * CHW;
    ushort* h1 = hb1 + (size_t)b * CHW;
    float*  cb = cell + (size_t)b * CHW;

    const int gy_ = ty0 + 4 * w;
    const int gx_ = tx0 + quad * 4;
    const ushort* wq = Wt + (size_t)q * 18432;

    // cell lives in registers across all 16 steps
    f32x4 cpv[4];
    #pragma unroll
    for (int r = 0; r < 4; ++r)
        cpv[r] = (f32x4){0.f, 0.f, 0.f, 0.f};

    for (int t = 0; t < 16; ++t) {
        const ushort* xt = xb + ((size_t)b * 16 + t) * CHW;
        const ushort* hi = (t & 1) ? h1 : h0;   // written at step t-1
        ushort*       ho = (t & 1) ? h0 : h1;

        f32x4 acc[4][4];
        #pragma unroll
        for (int r = 0; r < 4; ++r)
            #pragma unroll
            for (int g = 0; g < 4; ++g)
                acc[r][g] = (f32x4){0.f, 0.f, 0.f, 0.f};

        // chunk sources: 0,1 -> x channels 0-31/32-63; 2,3 -> h channels 0-31/32-63
        stage_chunk<false>(zs, xt, tid, ty0, tx0);
        __syncthreads();

        #pragma unroll
        for (int cix = 0; cix < 4; ++cix) {
            ushort* cur = zs + (cix & 1) * ZSZ;
            ushort* nxt = zs + ((cix + 1) & 1) * ZSZ;

            // stage next chunk into the idle buffer (no barrier: nxt unread
            // this iter); compiler interleaves these with the MFMAs below.
            if (cix == 0) stage_chunk<false>(nxt, xt + 32, tid, ty0, tx0);
            else if (cix == 1) stage_chunk<true>(nxt, hi, tid, ty0, tx0);
            else if (cix == 2) stage_chunk<true>(nxt, hi + 32, tid, ty0, tx0);

            const ushort* wb = wq + (size_t)cix * 4 * 18432;
            #pragma unroll
            for (int kx = 0; kx < 3; ++kx) {
                bf16x8 arow[6];
                #pragma unroll
                for (int j = 0; j < 6; ++j)
                    arow[j] = *(const bf16x8*)&cur[((4 * w + j) * 18 + col + kx) * 40 + q8];
                #pragma unroll
                for (int ky = 0; ky < 3; ++ky) {
                    const int tap = ky * 3 + kx;
                    bf16x8 bfr[4];
                    #pragma unroll
                    for (int g = 0; g < 4; ++g)
                        bfr[g] = *(const bf16x8*)(wb + (size_t)tap * 2048 + g * 512 + lane * 8);
                    #pragma unroll
                    for (int g = 0; g < 4; ++g)
                        #pragma unroll
                        for (int r = 0; r < 4; ++r)
                            acc[r][g] = __builtin_amdgcn_mfma_f32_16x16x32_bf16(
                                arow[r + ky], bfr[g], acc[r][g], 0, 0, 0);
                }
            }
            __syncthreads();   // nxt fully written & cur fully read before swap
        }

        // epilogue: gates + state update; cell stays in registers
        #pragma unroll
        for (int r = 0; r < 4; ++r) {
            const size_t rowbase = ((size_t)(gy_ + r) * 64 + gx_) * 64 + hc0 + col;
            #pragma unroll
            for (int reg = 0; reg < 4; ++reg) {
                const float ci  = acc[r][0][reg];
                const float cf  = acc[r][1][reg];
                const float co  = acc[r][2][reg];
                const float cgv = acc[r][3][reg];
                const float cn  = sigf(cf) * cpv[r][reg] + sigf(ci) * tanhf(cgv);
                const float hn  = sigf(co) * tanhf(cn);
                cpv[r][reg] = cn;
                ho[rowbase + (size_t)reg * 64] = f2bf(hn);
                if (t == 15) cb[rowbase + (size_t)reg * 64] = cn;
            }
        }

        if (t < 15) {
            // ---- per-batch grid barrier, no cache invalidation ----
            // __syncthreads: all waves' h stores issued (wave-level vmcnt(0)
            // drain before s_barrier). Release RMW by tid0: buffer_wbl2
            // (write-back L2 -> Infinity Cache, lines stay valid) + atomic.
            // No acquire fence needed: h reads next step are agent-scope
            // atomic loads served from the IF coherence point.
            __syncthreads();
            if (tid == 0) {
                unsigned* c = &bar[t * 8 + b];
                __hip_atomic_fetch_add(c, 1u, __ATOMIC_RELEASE,
                                       __HIP_MEMORY_SCOPE_AGENT);
                while (__hip_atomic_load(c, __ATOMIC_RELAXED,
                                         __HIP_MEMORY_SCOPE_AGENT) < BBLK)
                    __builtin_amdgcn_s_sleep(2);
            }
            __syncthreads();
        }
    }
}

// NHWC -> NCHW final outputs: d_out = [h fp32 | c fp32], each (8,64,4096)
__global__ __launch_bounds__(256) void conv_out(
    const ushort* __restrict__ hN, const float* __restrict__ cN,
    float* __restrict__ out)
{
    __shared__ float T[64][65];
    const int tid  = threadIdx.x;
    const int pg   = blockIdx.x;        // 64 pixel-groups of 64
    const int b    = blockIdx.y;
    const int tsel = blockIdx.z;        // 0 = h, 1 = c
    const int pix0 = pg * 64;

    #pragma unroll
    for (int k = 0; k < 16; ++k) {
        const int idx = k * 256 + tid;
        const int pl = idx >> 6, ch = idx & 63;
        const size_t src = (size_t)b * CHW + (size_t)(pix0 + pl) * 64 + ch;
        T[pl][ch] = tsel ? cN[src] : bf2f(hN[src]);
    }
    __syncthreads();
    float* base = out + (tsel ? 2097152 : 0);
    #pragma unroll
    for (int k = 0; k < 16; ++k) {
        const int idx = k * 256 + tid;
        const int ch = idx >> 6, pl = idx & 63;
        base[(size_t)b * CHW + (size_t)ch * 4096 + pix0 + pl] = T[pl][ch];
    }
}

extern "C" void kernel_launch(void* const* d_in, const int* in_sizes, int n_in,
                              void* d_out, int out_size, void* d_ws, size_t ws_size,
                              hipStream_t stream) {
    const float* x  = (const float*)d_in[0];
    const float* Wk = (const float*)d_in[1];
    float* out = (float*)d_out;

    char* ws = (char*)d_ws;
    ushort*   Wt  = (ushort*)ws;                       // 589,824 B @ 0
    unsigned* bar = (unsigned*)(ws + 917504);          // 480 B @ 896 KB
    float*    cb  = (float*)(ws + (1u << 20));         // 8,388,608 B @ 1 MB
    ushort*   hb0 = (ushort*)(ws + (16u << 20));       // 4,194,304 B @ 16 MB
    ushort*   hb1 = (ushort*)(ws + (20u << 20));       // 4,194,304 B @ 20 MB
    ushort*   xb  = (ushort*)(ws + (32u << 20));       // 67,108,864 B @ 32 MB

    (void)hipMemsetAsync(hb0, 0, 4194304, stream);     // h(-1) = 0
    (void)hipMemsetAsync(bar, 0, 512, stream);         // barrier counters
    transform_w<<<144, 256, 0, stream>>>(Wk, Wt);
    xconv<<<dim3(16, 128), 256, 0, stream>>>(x, xb);

    convlstm_all<<<dim3(16, 4, 8), 256, 0, stream>>>(xb, Wt, hb0, hb1, cb, bar);

    // t=15 wrote hb0
    conv_out<<<dim3(64, 8, 2), 256, 0, stream>>>(hb0, cb, out);
}

// Round 4
// 1626.968 us; speedup vs baseline: 1.6364x; 1.3029x over previous
//
#include <hip/hip_runtime.h>
#include <cmath>

// ConvLSTM round 11: persistent kernel, XCD-local batches + fence-free coherence.
// Round-10 post-mortem: FETCH stayed 2.37 GB without the inv -> refetch was
// L2 THRASH: per-XCD streaming (64 blocks x 83 KB x/h per step) turned over
// the 4 MB L2 every step, evicting the 576 KB weight set between uses
// (1.18 GB of weight refetch); plus 512 release-RMWs/step each lowering to a
// full buffer_wbl2 L2 walk. Fixes:
//  1) 1-D grid, b = blockIdx.x & 7: round-robin dispatch puts all 64 blocks
//     of batch b on XCD b -> per-XCD streaming ~1.3 MB/step << 4 MB L2 ->
//     weights stay resident; 4x-duplicated x/h tile reads become L2 hits.
//     (Locality only -- correctness never depends on the mapping.)
//  2) h released via agent-scope relaxed ATOMIC STORES (write-through to the
//     IF coherence point). No release fence, no wbl2 walk.
//  3) Barrier is counter-only relaxed atomics on 64B-padded per-(t,b)
//     counters; h-store visibility is ordered by the per-wave vmcnt(0) drain
//     at __syncthreads before tid0's arrive. h loads stay sc1 (coherent at
//     IF regardless of XCD mapping).
// Cell state stays in registers for all 16 steps.

#define CHW 262144             // 64*64*64
#define ZSZ 12960              // ushorts per z buffer (324*40)
#define BBLK 64u               // blocks per batch (16 tiles x 4 quarters)

typedef short bf16x8 __attribute__((ext_vector_type(8)));
typedef float f32x4  __attribute__((ext_vector_type(4)));

static __device__ __forceinline__ ushort f2bf(float f) {
    union { float f; unsigned u; } v; v.f = f;
    unsigned u = v.u;
    return (ushort)((u + 0x7FFFu + ((u >> 16) & 1u)) >> 16);
}
static __device__ __forceinline__ float bf2f(ushort u) {
    union { unsigned u; float f; } v; v.u = (unsigned)u << 16; return v.f;
}
static __device__ __forceinline__ float sigf(float x) {
    return 1.f / (1.f + __expf(-x));
}

// Wt layout: [cq = cix*4+q][tap][g][lane][8j] (ushort).
// element = bf16(Wk[oc = g*64+q*16+(lane&15)][ic = cix*32+(lane>>4)*8+j][ky][kx])
__global__ void transform_w(const float* __restrict__ Wk, ushort* __restrict__ Wt) {
    const int idx  = blockIdx.x * 256 + threadIdx.x;   // 0..36863
    const int lane = idx & 63;
    const int g    = (idx >> 6) & 3;
    const int r2   = idx >> 8;
    const int tap  = r2 % 9;
    const int cq   = r2 / 9;
    const int q    = cq & 3;
    const int cix  = cq >> 2;
    const int oc   = g * 64 + q * 16 + (lane & 15);
    const int icb  = cix * 32 + (lane >> 4) * 8;
    const int ky   = tap / 3, kx = tap - ky * 3;
    ushort* dst = Wt + (size_t)idx * 8;
    #pragma unroll
    for (int j = 0; j < 8; ++j)
        dst[j] = f2bf(Wk[((size_t)(oc * 128 + icb + j) * 3 + ky) * 3 + kx]);
}

// x (8,16,64,64,64) fp32 NCHW -> xb (8,16,4096,64) bf16 NHWC (per bt volume)
__global__ __launch_bounds__(256) void xconv(const float* __restrict__ x,
                                             ushort* __restrict__ xb) {
    __shared__ ushort T[256 * 66];
    const int tid = threadIdx.x;
    const int pg  = blockIdx.x;        // 16 pixel-groups of 256
    const int bt  = blockIdx.y;        // 128
    const float* xt = x  + (size_t)bt * CHW;
    ushort*      xo = xb + (size_t)bt * CHW;
    const int p0 = pg * 256;
    #pragma unroll
    for (int ch = 0; ch < 64; ++ch)
        T[tid * 66 + ch] = f2bf(xt[(size_t)ch * 4096 + p0 + tid]);
    __syncthreads();
    #pragma unroll
    for (int k = 0; k < 64; ++k) {
        const int item = k * 256 + tid;
        const int px = item >> 6, ch = item & 63;
        xo[(size_t)(p0 + px) * 64 + ch] = T[px * 66 + ch];
    }
}

// stage one 32-channel haloed 18x18 chunk from NHWC bf16 src into LDS buffer.
// COH=true: agent-scope coherent loads (h, written by other blocks this
// kernel -- always correct, independent of XCD placement). COH=false: plain
// cached loads (x, weights-era data).
template <bool COH>
static __device__ __forceinline__ void stage_chunk(
    ushort* __restrict__ dst, const ushort* __restrict__ src,
    int tid, int ty0, int tx0) {
    #pragma unroll
    for (int k = 0; k < 11; ++k) {
        const int i = tid + k * 256;
        if (i < 2592) {
            const int p   = i >> 3;
            const int icq = i & 7;
            const int py  = p / 18;
            const int pxl = p - py * 18;
            const int gy  = ty0 + py - 1;
            const int gx  = tx0 + pxl - 1;
            ushort4 v = {0, 0, 0, 0};
            if (((unsigned)gy < 64u) & ((unsigned)gx < 64u)) {
                const size_t off = (size_t)(gy * 64 + gx) * 64 + icq * 4;
                if constexpr (COH) {
                    union { unsigned long long u; ushort4 v4; } cv;
                    cv.u = __hip_atomic_load(
                        (const unsigned long long*)&src[off],
                        __ATOMIC_RELAXED, __HIP_MEMORY_SCOPE_AGENT);
                    v = cv.v4;
                } else {
                    v = *(const ushort4*)&src[off];
                }
            }
            *(ushort4*)&dst[p * 40 + icq * 4] = v;
        }
    }
}

__global__ __launch_bounds__(256, 2) void convlstm_all(
    const ushort* __restrict__ xb,    // (8,16,4096,64) bf16 NHWC
    const ushort* __restrict__ Wt,    // fragment-ordered bf16 weights
    ushort*       __restrict__ hb0,   // (8,4096,64) bf16 NHWC ping
    ushort*       __restrict__ hb1,   // (8,4096,64) bf16 NHWC pong
    float*        __restrict__ cell,  // (8,4096,64) fp32 NHWC, final only
    unsigned*     __restrict__ bar)   // 15*8 per-(step,batch) counters, 64B apart
{
    __shared__ __align__(16) ushort zs[2 * ZSZ];      // 51,840 B double buffer

    const int tid  = threadIdx.x;
    const int lane = tid & 63;
    const int w    = tid >> 6;
    const int col  = lane & 15;
    const int quad = lane >> 4;
    const int q8   = quad * 8;

    // 1-D grid decode: b fastest -> round-robin dispatch puts batch b on XCD b
    const int bid  = blockIdx.x;
    const int b    = bid & 7;
    const int tile = (bid >> 3) & 15;
    const int q    = bid >> 7;

    const int ty0  = (tile >> 2) * 16;
    const int tx0  = (tile & 3) * 16;
    const int hc0  = q * 16;

    ushort* h0 = hb0 + (size_t)b * CHW;
    ushort* h1 = hb1 + (size_t)b * CHW;
    float*  cb = cell + (size_t)b * CHW;

    const int gy_ = ty0 + 4 * w;
    const int gx_ = tx0 + quad * 4;
    const ushort* wq = Wt + (size_t)q * 18432;

    // cell lives in registers across all 16 steps
    f32x4 cpv[4];
    #pragma unroll
    for (int r = 0; r < 4; ++r)
        cpv[r] = (f32x4){0.f, 0.f, 0.f, 0.f};

    for (int t = 0; t < 16; ++t) {
        const ushort* xt = xb + ((size_t)b * 16 + t) * CHW;
        const ushort* hi = (t & 1) ? h1 : h0;   // written at step t-1
        ushort*       ho = (t & 1) ? h0 : h1;

        f32x4 acc[4][4];
        #pragma unroll
        for (int r = 0; r < 4; ++r)
            #pragma unroll
            for (int g = 0; g < 4; ++g)
                acc[r][g] = (f32x4){0.f, 0.f, 0.f, 0.f};

        // chunk sources: 0,1 -> x channels 0-31/32-63; 2,3 -> h channels 0-31/32-63
        stage_chunk<false>(zs, xt, tid, ty0, tx0);
        __syncthreads();

        #pragma unroll
        for (int cix = 0; cix < 4; ++cix) {
            ushort* cur = zs + (cix & 1) * ZSZ;
            ushort* nxt = zs + ((cix + 1) & 1) * ZSZ;

            // stage next chunk into the idle buffer (no barrier: nxt unread
            // this iter); compiler interleaves these with the MFMAs below.
            if (cix == 0) stage_chunk<false>(nxt, xt + 32, tid, ty0, tx0);
            else if (cix == 1) stage_chunk<true>(nxt, hi, tid, ty0, tx0);
            else if (cix == 2) stage_chunk<true>(nxt, hi + 32, tid, ty0, tx0);

            const ushort* wb = wq + (size_t)cix * 4 * 18432;
            #pragma unroll
            for (int kx = 0; kx < 3; ++kx) {
                bf16x8 arow[6];
                #pragma unroll
                for (int j = 0; j < 6; ++j)
                    arow[j] = *(const bf16x8*)&cur[((4 * w + j) * 18 + col + kx) * 40 + q8];
                #pragma unroll
                for (int ky = 0; ky < 3; ++ky) {
                    const int tap = ky * 3 + kx;
                    bf16x8 bfr[4];
                    #pragma unroll
                    for (int g = 0; g < 4; ++g)
                        bfr[g] = *(const bf16x8*)(wb + (size_t)tap * 2048 + g * 512 + lane * 8);
                    #pragma unroll
                    for (int g = 0; g < 4; ++g)
                        #pragma unroll
                        for (int r = 0; r < 4; ++r)
                            acc[r][g] = __builtin_amdgcn_mfma_f32_16x16x32_bf16(
                                arow[r + ky], bfr[g], acc[r][g], 0, 0, 0);
                }
            }
            __syncthreads();   // nxt fully written & cur fully read before swap
        }

        // epilogue: gates + state update; cell stays in registers.
        // h stores are agent-scope write-through (visible at IF, no fence).
        #pragma unroll
        for (int r = 0; r < 4; ++r) {
            const size_t rowbase = ((size_t)(gy_ + r) * 64 + gx_) * 64 + hc0 + col;
            #pragma unroll
            for (int reg = 0; reg < 4; ++reg) {
                const float ci  = acc[r][0][reg];
                const float cf  = acc[r][1][reg];
                const float co  = acc[r][2][reg];
                const float cgv = acc[r][3][reg];
                const float cn  = sigf(cf) * cpv[r][reg] + sigf(ci) * tanhf(cgv);
                const float hn  = sigf(co) * tanhf(cn);
                cpv[r][reg] = cn;
                __hip_atomic_store(&ho[rowbase + (size_t)reg * 64], f2bf(hn),
                                   __ATOMIC_RELAXED, __HIP_MEMORY_SCOPE_AGENT);
                if (t == 15) cb[rowbase + (size_t)reg * 64] = cn;
            }
        }

        if (t < 15) {
            // ---- per-batch grid barrier, counter-only, no fences ----
            // __syncthreads drains each wave's h stores (vmcnt(0)) to the IF
            // coherence point BEFORE tid0 arrives; readers use sc1 loads.
            __syncthreads();
            if (tid == 0) {
                unsigned* c = &bar[(t * 8 + b) * 16];   // 64B-padded counter
                __hip_atomic_fetch_add(c, 1u, __ATOMIC_RELAXED,
                                       __HIP_MEMORY_SCOPE_AGENT);
                while (__hip_atomic_load(c, __ATOMIC_RELAXED,
                                         __HIP_MEMORY_SCOPE_AGENT) < BBLK)
                    __builtin_amdgcn_s_sleep(2);
            }
            __syncthreads();
        }
    }
}

// NHWC -> NCHW final outputs: d_out = [h fp32 | c fp32], each (8,64,4096)
__global__ __launch_bounds__(256) void conv_out(
    const ushort* __restrict__ hN, const float* __restrict__ cN,
    float* __restrict__ out)
{
    __shared__ float T[64][65];
    const int tid  = threadIdx.x;
    const int pg   = blockIdx.x;        // 64 pixel-groups of 64
    const int b    = blockIdx.y;
    const int tsel = blockIdx.z;        // 0 = h, 1 = c
    const int pix0 = pg * 64;

    #pragma unroll
    for (int k = 0; k < 16; ++k) {
        const int idx = k * 256 + tid;
        const int pl = idx >> 6, ch = idx & 63;
        const size_t src = (size_t)b * CHW + (size_t)(pix0 + pl) * 64 + ch;
        T[pl][ch] = tsel ? cN[src] : bf2f(hN[src]);
    }
    __syncthreads();
    float* base = out + (tsel ? 2097152 : 0);
    #pragma unroll
    for (int k = 0; k < 16; ++k) {
        const int idx = k * 256 + tid;
        const int ch = idx >> 6, pl = idx & 63;
        base[(size_t)b * CHW + (size_t)ch * 4096 + pix0 + pl] = T[pl][ch];
    }
}

extern "C" void kernel_launch(void* const* d_in, const int* in_sizes, int n_in,
                              void* d_out, int out_size, void* d_ws, size_t ws_size,
                              hipStream_t stream) {
    const float* x  = (const float*)d_in[0];
    const float* Wk = (const float*)d_in[1];
    float* out = (float*)d_out;

    char* ws = (char*)d_ws;
    ushort*   Wt  = (ushort*)ws;                       // 589,824 B @ 0
    unsigned* bar = (unsigned*)(ws + 917504);          // 7,680 B @ 896 KB
    float*    cb  = (float*)(ws + (1u << 20));         // 8,388,608 B @ 1 MB
    ushort*   hb0 = (ushort*)(ws + (16u << 20));       // 4,194,304 B @ 16 MB
    ushort*   hb1 = (ushort*)(ws + (20u << 20));       // 4,194,304 B @ 20 MB
    ushort*   xb  = (ushort*)(ws + (32u << 20));       // 67,108,864 B @ 32 MB

    (void)hipMemsetAsync(hb0, 0, 4194304, stream);     // h(-1) = 0
    (void)hipMemsetAsync(bar, 0, 8192, stream);        // barrier counters
    transform_w<<<144, 256, 0, stream>>>(Wk, Wt);
    xconv<<<dim3(16, 128), 256, 0, stream>>>(x, xb);

    convlstm_all<<<512, 256, 0, stream>>>(xb, Wt, hb0, hb1, cb, bar);

    // t=15 wrote hb0
    conv_out<<<dim3(64, 8, 2), 256, 0, stream>>>(hb0, cb, out);
}